// Round 3
// baseline (1598.508 us; speedup 1.0000x reference)
//
#include <hip/hip_runtime.h>
#include <hip/hip_bf16.h>

#define NB 16
#define VIN 40962
#define VP 10242
#define EPSbn 1e-5f

// ---------------- workspace layouts (bytes) ----------------
// Base path (ws >= WS_NEED):
//   shared buf at 0: h0 (42MB, pool..conv1) then y2 (84MB, conv2..bnout)
//   y1 lives in d_out. stats at OFF_ST.
// Fast path (ws >= WS_BIG): adds explicit x-transpose.
//   xT at 0 (168MB, transpose..pool); h0 in d_out (42MB, pool..conv1);
//   y1 at 0 (84MB, conv1..conv2; xT dead);  y2 at 84MB; stats at OFF_ST_BIG.
static constexpr size_t SZ_H0 = (size_t)NB * VP * 64 * 4;     // 41,951,232
static constexpr size_t SZ_Y  = (size_t)NB * VP * 128 * 4;    // 83,902,464
static constexpr size_t SZ_XT = (size_t)NB * VIN * 64 * 4;    // 167,771,136
static constexpr size_t SZ_ST = 8 * (size_t)NB * 128 * 4;     // 65,536

static constexpr size_t OFF_ST     = ((SZ_Y + 255) & ~(size_t)255);
static constexpr size_t WS_NEED    = OFF_ST + SZ_ST;

static constexpr size_t OFF_Y2_BIG = ((SZ_Y + 255) & ~(size_t)255);        // y1:[0,84M) y2:[84M,168M)
static constexpr size_t OFF_ST_BIG = ((OFF_Y2_BIG + SZ_Y + 255) & ~(size_t)255);
static constexpr size_t WS_BIG     = OFF_ST_BIG + SZ_ST;                   // ~160.1 MiB

// ---------------- tiled transpose: x (B,64,VIN) -> xT (B,VIN,64) ----------------
__global__ void k_transpose(const float* __restrict__ x, float* __restrict__ xT)
{
    __shared__ float t[64][65];                 // +1 pad -> conflict-free both phases
    const int b   = blockIdx.y;
    const int v0  = blockIdx.x * 64;
    const int tid = threadIdx.x;                // 256
    const int lc  = tid & 63;                   // vin offset (load), channel (store)
    const int lw  = tid >> 6;                   // wave id 0..3
    const float* xb = x + (size_t)b * 64 * VIN;
#pragma unroll
    for (int u = 0; u < 16; ++u) {
        const int c = lw * 16 + u;
        const int v = v0 + lc;
        t[c][lc] = (v < VIN) ? xb[(size_t)c * VIN + v] : 0.f;
    }
    __syncthreads();
    float* xTb = xT + (size_t)b * VIN * 64;
#pragma unroll
    for (int u = 0; u < 16; ++u) {
        const int v = v0 + lw * 16 + u;
        if (v < VIN) xTb[(size_t)v * 64 + lc] = t[lc][lw * 16 + u];
    }
}

// ---------------- mean-pool from transposed x: coalesced 256B row gathers ----------------
__global__ void k_pool_fast(const float* __restrict__ xT, const int* __restrict__ pidx,
                            float* __restrict__ h0)
{
    const int b  = blockIdx.y;
    const int vp = blockIdx.x * 4 + (threadIdx.x >> 6);
    const int c  = threadIdx.x & 63;
    if (vp >= VP) return;
    const float* xb = xT + (size_t)b * VIN * 64;
    float s = 0.f;
#pragma unroll
    for (int j = 0; j < 7; ++j) {
        const int id = pidx[vp * 7 + j];
        s += xb[(size_t)id * 64 + c];
    }
    h0[((size_t)b * VP + vp) * 64 + c] = s * (1.f / 7.f);
}

// ---------------- mean-pool directly from x (fallback; strided gather) ----------------
__global__ void k_pool(const float* __restrict__ x, const int* __restrict__ pidx,
                       float* __restrict__ h0)
{
    const int b  = blockIdx.y;
    const int vp = blockIdx.x * 4 + (threadIdx.x >> 6);
    const int c  = threadIdx.x & 63;
    if (vp >= VP) return;
    const float* xb = x + (size_t)(b * 64) * VIN;
    float s = 0.f;
#pragma unroll
    for (int j = 0; j < 7; ++j) {
        const int id = pidx[vp * 7 + j];
        s += xb[(size_t)c * VIN + id];
    }
    h0[((size_t)b * VP + vp) * 64 + c] = s * (1.f / 7.f);
}

// ---------------- gather + GEMM (+optional fused BN1+LReLU on input) ----------------
// BM=128, BN=128, BK=32, 128 threads, 8 rows x 16 cols per thread.
template<int CIN, bool FUSE, bool STORE_T>
__global__ __launch_bounds__(128, 2)
void k_conv(const float* __restrict__ src, const int* __restrict__ nidx,
            const float* __restrict__ W, const float* __restrict__ bias,
            const float* __restrict__ sc_in, const float* __restrict__ sh_in,
            float* __restrict__ y, float* __restrict__ gsum, float* __restrict__ gsq)
{
    constexpr int NKT   = (7 * CIN) / 32;   // 14 (conv1) / 28 (conv2)
    constexpr int PER_N = CIN / 32;         // k-tiles per neighbor
    __shared__ float gT[32][129];           // [kk][row]
    __shared__ float wT[32][132];           // [kk][col]

    const int b   = blockIdx.y;
    const int vp0 = blockIdx.x * 128;
    const int tid = threadIdx.x;
    const int tr  = tid & 15;               // row group (rows tr+16i)
    const int tc  = tid >> 4;               // col group (cols tc*16+n)

    float acc[8][16];
#pragma unroll
    for (int i = 0; i < 8; ++i)
#pragma unroll
        for (int n = 0; n < 16; ++n) acc[i][n] = 0.f;

    const float* srcb  = src + (size_t)b * VP * CIN;
    const int f     = tid & 7;              // g-stage float4 slot
    const int rbase = tid >> 3;             // g-stage row base (0..15)
    const int wc    = tid & 31;             // w-stage float4 col
    const int wr    = tid >> 5;             // w-stage row base (0..3)

    for (int t = 0; t < NKT; ++t) {
        const int j  = t / PER_N;
        const int c0 = (t % PER_N) * 32;
        const int k0 = t * 32;
        float4 s4, h4;
        if constexpr (FUSE) {
            s4 = *(const float4*)(sc_in + b * 128 + c0 + 4 * f);
            h4 = *(const float4*)(sh_in + b * 128 + c0 + 4 * f);
        }
        __syncthreads();
        // stage gathered A-tile (transposed into gT[kk][row])
#pragma unroll
        for (int p = 0; p < 8; ++p) {
            const int lr = rbase + 16 * p;
            const int vp = vp0 + lr;
            const int id = (vp < VP) ? nidx[vp * 7 + j] : 0;
            float4 v = *(const float4*)(srcb + (size_t)id * CIN + c0 + 4 * f);
            if constexpr (FUSE) {
                v.x = fmaf(v.x, s4.x, h4.x); v.x = (v.x >= 0.f) ? v.x : 0.2f * v.x;
                v.y = fmaf(v.y, s4.y, h4.y); v.y = (v.y >= 0.f) ? v.y : 0.2f * v.y;
                v.z = fmaf(v.z, s4.z, h4.z); v.z = (v.z >= 0.f) ? v.z : 0.2f * v.z;
                v.w = fmaf(v.w, s4.w, h4.w); v.w = (v.w >= 0.f) ? v.w : 0.2f * v.w;
            }
            gT[4 * f + 0][lr] = v.x;
            gT[4 * f + 1][lr] = v.y;
            gT[4 * f + 2][lr] = v.z;
            gT[4 * f + 3][lr] = v.w;
        }
        // stage W-tile
#pragma unroll
        for (int u = 0; u < 8; ++u) {
            const int kk = wr + 4 * u;
            float4 wv = *(const float4*)(W + (size_t)(k0 + kk) * 128 + 4 * wc);
            *(float4*)&wT[kk][4 * wc] = wv;
        }
        __syncthreads();
        // compute
#pragma unroll 2
        for (int kk = 0; kk < 32; ++kk) {
            float a[8];
#pragma unroll
            for (int i = 0; i < 8; ++i) a[i] = gT[kk][tr + 16 * i];
            float bb[16];
#pragma unroll
            for (int u = 0; u < 4; ++u) {
                float4 w4 = *(const float4*)&wT[kk][tc * 16 + 4 * u];
                bb[4*u+0] = w4.x; bb[4*u+1] = w4.y; bb[4*u+2] = w4.z; bb[4*u+3] = w4.w;
            }
#pragma unroll
            for (int i = 0; i < 8; ++i)
#pragma unroll
                for (int n = 0; n < 16; ++n)
                    acc[i][n] = fmaf(a[i], bb[n], acc[i][n]);
        }
    }

    // ---- epilogue: +bias, store, per-channel partial stats ----
    float bia[16];
#pragma unroll
    for (int n = 0; n < 16; ++n) bia[n] = bias[tc * 16 + n];
    float ssum[16], ssq[16];
#pragma unroll
    for (int n = 0; n < 16; ++n) { ssum[n] = 0.f; ssq[n] = 0.f; }

#pragma unroll
    for (int i = 0; i < 8; ++i) {
        const int vp = vp0 + tr + 16 * i;
        const bool val = (vp < VP);
#pragma unroll
        for (int n = 0; n < 16; ++n) {
            float v = acc[i][n] + bia[n];
            acc[i][n] = v;
            if (val) { ssum[n] += v; ssq[n] += v * v; }
        }
        if (val) {
            if constexpr (STORE_T) {
#pragma unroll
                for (int n = 0; n < 16; ++n)
                    y[(size_t)(b * 128 + tc * 16 + n) * VP + vp] = acc[i][n];
            } else {
                float* yr = y + ((size_t)b * VP + vp) * 128 + tc * 16;
#pragma unroll
                for (int u = 0; u < 4; ++u) {
                    float4 st = { acc[i][4*u+0], acc[i][4*u+1], acc[i][4*u+2], acc[i][4*u+3] };
                    *(float4*)(yr + 4 * u) = st;
                }
            }
        }
    }
    // reduce stats over the 16 row-group lanes (contiguous lanes in-wave)
#pragma unroll
    for (int d = 8; d >= 1; d >>= 1) {
#pragma unroll
        for (int n = 0; n < 16; ++n) {
            ssum[n] += __shfl_xor(ssum[n], d, 64);
            ssq[n]  += __shfl_xor(ssq[n],  d, 64);
        }
    }
    if (tr == 0) {
#pragma unroll
        for (int n = 0; n < 16; ++n) {
            atomicAdd(&gsum[b * 128 + tc * 16 + n], ssum[n]);
            atomicAdd(&gsq [b * 128 + tc * 16 + n], ssq[n]);
        }
    }
}

// ---------------- BN stats -> per-(b,ch) affine ----------------
__global__ void k_finalize(const float* __restrict__ gsum, const float* __restrict__ gsq,
                           const float* __restrict__ gam, const float* __restrict__ bet,
                           float* __restrict__ scale, float* __restrict__ shift)
{
    const int i = blockIdx.x * 256 + threadIdx.x;
    if (i >= NB * 128) return;
    const int o = i & 127;
    const float m   = gsum[i] * (1.f / VP);
    const float var = gsq[i] * (1.f / VP) - m * m;
    const float sc  = gam[o] * rsqrtf(var + EPSbn);
    scale[i] = sc;
    shift[i] = fmaf(-m, sc, bet[o]);
}

// ---------------- BN2 + LReLU:  y2 (transposed) -> d_out ----------------
__global__ void k_bnout(const float* __restrict__ y2, float* __restrict__ out,
                        const float* __restrict__ scale, const float* __restrict__ shift)
{
    const int bo = blockIdx.x;              // b*128 + o
    const float sc = scale[bo], sh = shift[bo];
    const float* p = y2 + (size_t)bo * VP;
    float* q = out + (size_t)bo * VP;
    for (int v = threadIdx.x; v < VP; v += 256) {
        float xv = fmaf(p[v], sc, sh);
        q[v] = (xv >= 0.f) ? xv : 0.2f * xv;
    }
}

extern "C" void kernel_launch(void* const* d_in, const int* in_sizes, int n_in,
                              void* d_out, int out_size, void* d_ws, size_t ws_size,
                              hipStream_t stream)
{
    (void)in_sizes; (void)n_in; (void)out_size;
    const float* x   = (const float*)d_in[0];
    const int*   pidx= (const int*)d_in[1];
    const int*   nidx= (const int*)d_in[2];
    const float* W1  = (const float*)d_in[3];
    const float* b1  = (const float*)d_in[4];
    const float* g1  = (const float*)d_in[5];
    const float* be1 = (const float*)d_in[6];
    const float* W2  = (const float*)d_in[7];
    const float* b2  = (const float*)d_in[8];
    const float* g2  = (const float*)d_in[9];
    const float* be2 = (const float*)d_in[10];
    float* out = (float*)d_out;
    char*  ws  = (char*)d_ws;

    if (ws_size < WS_NEED) return;  // clean bail: wrong answer, not a memory fault
    const bool big = (ws_size >= WS_BIG);

    float *h0, *y1, *y2, *st;
    if (big) {
        h0 = out;                            // pool..conv1 (d_out as scratch)
        y1 = (float*)(ws + 0);               // conv1..conv2 (overlaps dead xT)
        y2 = (float*)(ws + OFF_Y2_BIG);      // conv2..bnout
        st = (float*)(ws + OFF_ST_BIG);
    } else {
        h0 = (float*)(ws + 0);               // pool..conv1
        y1 = out;                            // conv1..conv2 (d_out as scratch)
        y2 = (float*)(ws + 0);               // conv2..bnout (overlaps dead h0)
        st = (float*)(ws + OFF_ST);
    }
    float* sum1 = st;          float* sq1 = st + 2048;
    float* sum2 = st + 4096;   float* sq2 = st + 6144;
    float* sc1  = st + 8192;   float* sh1 = st + 10240;
    float* sc2  = st + 12288;  float* sh2 = st + 14336;

    hipMemsetAsync(st, 0, 4 * 2048 * sizeof(float), stream);

    dim3 gpool((VP + 3) / 4, NB);
    if (big) {
        float* xT = (float*)(ws + 0);        // transpose..pool
        dim3 gt((VIN + 63) / 64, NB);
        k_transpose<<<gt, 256, 0, stream>>>(x, xT);
        k_pool_fast<<<gpool, 256, 0, stream>>>(xT, pidx, h0);
    } else {
        k_pool<<<gpool, 256, 0, stream>>>(x, pidx, h0);
    }

    dim3 gconv((VP + 127) / 128, NB);
    k_conv<64, false, false><<<gconv, 128, 0, stream>>>(h0, nidx, W1, b1, nullptr, nullptr,
                                                        y1, sum1, sq1);
    k_finalize<<<8, 256, 0, stream>>>(sum1, sq1, g1, be1, sc1, sh1);
    k_conv<128, true, true><<<gconv, 128, 0, stream>>>(y1, nidx, W2, b2, sc1, sh1,
                                                       y2, sum2, sq2);
    k_finalize<<<8, 256, 0, stream>>>(sum2, sq2, g2, be2, sc2, sh2);
    k_bnout<<<2048, 256, 0, stream>>>(y2, out, sc2, sh2);
}

// Round 4
// 1033.271 us; speedup vs baseline: 1.5470x; 1.5470x over previous
//
#include <hip/hip_runtime.h>
#include <hip/hip_bf16.h>

#define NB 16
#define VIN 40962
#define VP 10242
#define EPSbn 1e-5f

typedef __attribute__((ext_vector_type(8))) short bf16x8;  // 8 bf16 = 4 VGPR
typedef __attribute__((ext_vector_type(4))) float f32x4;   // MFMA C/D
typedef unsigned short u16;

// ---------------- workspace layout (bytes) ----------------
// wts2 [0, 458752)  wts1 [458752, 688128)  y1 [688128, +84MB)  stats  (xT optional)
static constexpr size_t OFF_W2 = 0;
static constexpr size_t OFF_W1 = 458752;
static constexpr size_t OFF_Y1 = 688128;
static constexpr size_t OFF_ST = OFF_Y1 + (size_t)NB * VP * 128 * 4;   // 84,590,592
static constexpr size_t WS_NEED = OFF_ST + 8 * (size_t)NB * 128 * 4;   // 84,656,128
static constexpr size_t OFF_XT = WS_NEED;
static constexpr size_t WS_FAST = OFF_XT + (size_t)NB * VIN * 64 * 4;  // ~252 MB

// ---------------- bf16 split helpers (RNE) ----------------
__device__ __forceinline__ u16 f2bf(float f) {
    unsigned u; __builtin_memcpy(&u, &f, 4);
    u = u + 0x7FFF + ((u >> 16) & 1);
    return (u16)(u >> 16);
}
__device__ __forceinline__ float bf2f(u16 h) {
    unsigned u = ((unsigned)h) << 16; float f; __builtin_memcpy(&f, &u, 4); return f;
}
__device__ __forceinline__ ushort2 splitf(float f) {
    u16 h = f2bf(f);
    u16 l = f2bf(f - bf2f(h));
    ushort2 r; r.x = h; r.y = l; return r;
}

// ---------------- W prep: W[K][128] f32 -> wts[o][2K] bf16 {hi-plane, lo-plane} ----------------
__global__ void k_wsplit(const float* __restrict__ W, u16* __restrict__ wts, int K)
{
    int idx = blockIdx.x * 256 + threadIdx.x;
    if (idx >= K * 128) return;
    int k = idx >> 7, o = idx & 127;
    ushort2 s = splitf(W[idx]);
    wts[(size_t)o * 2 * K + k]     = s.x;
    wts[(size_t)o * 2 * K + K + k] = s.y;
}

// ---------------- tiled transpose: x (B,64,VIN) -> xT (B,VIN,64) f32 ----------------
__global__ void k_transpose(const float* __restrict__ x, float* __restrict__ xT)
{
    __shared__ float t[64][65];
    const int b   = blockIdx.y;
    const int v0  = blockIdx.x * 64;
    const int tid = threadIdx.x;
    const int lc  = tid & 63;
    const int lw  = tid >> 6;
    const float* xb = x + (size_t)b * 64 * VIN;
#pragma unroll
    for (int u = 0; u < 16; ++u) {
        const int c = lw * 16 + u;
        const int v = v0 + lc;
        t[c][lc] = (v < VIN) ? xb[(size_t)c * VIN + v] : 0.f;
    }
    __syncthreads();
    float* xTb = xT + (size_t)b * VIN * 64;
#pragma unroll
    for (int u = 0; u < 16; ++u) {
        const int v = v0 + lw * 16 + u;
        if (v < VIN) xTb[(size_t)v * 64 + lc] = t[lc][lw * 16 + u];
    }
}

// ---------------- mean-pool -> h0s (B,VP,64 interleaved {hi,lo} pairs) ----------------
__global__ void k_pool_fast(const float* __restrict__ xT, const int* __restrict__ pidx,
                            u16* __restrict__ h0s)
{
    const int b  = blockIdx.y;
    const int vp = blockIdx.x * 4 + (threadIdx.x >> 6);
    const int c  = threadIdx.x & 63;
    if (vp >= VP) return;
    const float* xb = xT + (size_t)b * VIN * 64;
    float s = 0.f;
#pragma unroll
    for (int j = 0; j < 7; ++j) {
        const int id = pidx[vp * 7 + j];
        s += xb[(size_t)id * 64 + c];
    }
    s *= (1.f / 7.f);
    *(ushort2*)(h0s + ((size_t)b * VP + vp) * 128 + 2 * c) = splitf(s);
}

__global__ void k_pool_direct(const float* __restrict__ x, const int* __restrict__ pidx,
                              u16* __restrict__ h0s)
{
    const int b  = blockIdx.y;
    const int vp = blockIdx.x * 4 + (threadIdx.x >> 6);
    const int c  = threadIdx.x & 63;
    if (vp >= VP) return;
    const float* xb = x + (size_t)(b * 64) * VIN;
    float s = 0.f;
#pragma unroll
    for (int j = 0; j < 7; ++j) {
        const int id = pidx[vp * 7 + j];
        s += xb[(size_t)c * VIN + id];
    }
    s *= (1.f / 7.f);
    *(ushort2*)(h0s + ((size_t)b * VP + vp) * 128 + 2 * c) = splitf(s);
}

// ---------------- MFMA conv: gather + bf16x3 split GEMM ----------------
// src: rows of 2*CIN u16 interleaved pairs {hi,lo} per channel.
// wts: [128 out][2K] bf16, hi plane then lo plane. Block: 128 rows x 128 cols,
// 4 waves, each wave 32 rows x 128 cols (2 row-tiles x 8 col-tiles of 16x16).
// Barrier-free K-loop: frags loaded straight from global (L1/L2-resident).
template<int CIN, bool TRANSOUT>
__global__ __launch_bounds__(256, 2)
void k_convm(const u16* __restrict__ src, const int* __restrict__ nidx,
             const u16* __restrict__ wts, const float* __restrict__ bias,
             float* __restrict__ y, float* __restrict__ gsum, float* __restrict__ gsq)
{
    constexpr int K = 7 * CIN;
    __shared__ float lt[TRANSOUT ? 128 : 1][129];

    const int tid = threadIdx.x;
    const int w   = tid >> 6;
    const int l   = tid & 63;
    const int lg  = l >> 4;          // k-group for A/B frags; row-group for C/D
    const int lr  = l & 15;          // row (A) / col (B,C/D) within 16-tile
    const int b   = blockIdx.y;
    const int vp0 = blockIdx.x * 128;
    const int r0  = vp0 + w * 32;

    const u16* srcb = src + (size_t)b * VP * (2 * CIN);
    const int vc0 = (r0 + lr      < VP) ? (r0 + lr)      : (VP - 1);
    const int vc1 = (r0 + 16 + lr < VP) ? (r0 + 16 + lr) : (VP - 1);

    const u16* bb[8];
#pragma unroll
    for (int ct = 0; ct < 8; ++ct) bb[ct] = wts + (size_t)(ct * 16 + lr) * (2 * K);

    f32x4 acc[2][8];
#pragma unroll
    for (int t = 0; t < 2; ++t)
#pragma unroll
        for (int ct = 0; ct < 8; ++ct) acc[t][ct] = (f32x4){0.f, 0.f, 0.f, 0.f};

    for (int j = 0; j < 7; ++j) {
        const int id0 = nidx[vc0 * 7 + j];
        const int id1 = nidx[vc1 * 7 + j];
        const u16* a0 = srcb + (size_t)id0 * (2 * CIN);
        const u16* a1 = srcb + (size_t)id1 * (2 * CIN);
#pragma unroll
        for (int ks = 0; ks < CIN / 32; ++ks) {
            const int ko = ks * 32 + lg * 8;
            bf16x8 p00 = *(const bf16x8*)(a0 + 2 * ko);
            bf16x8 p01 = *(const bf16x8*)(a0 + 2 * ko + 8);
            bf16x8 p10 = *(const bf16x8*)(a1 + 2 * ko);
            bf16x8 p11 = *(const bf16x8*)(a1 + 2 * ko + 8);
            bf16x8 ah0 = {p00[0], p00[2], p00[4], p00[6], p01[0], p01[2], p01[4], p01[6]};
            bf16x8 al0 = {p00[1], p00[3], p00[5], p00[7], p01[1], p01[3], p01[5], p01[7]};
            bf16x8 ah1 = {p10[0], p10[2], p10[4], p10[6], p11[0], p11[2], p11[4], p11[6]};
            bf16x8 al1 = {p10[1], p10[3], p10[5], p10[7], p11[1], p11[3], p11[5], p11[7]};
            const int kw = j * CIN + ko;
#pragma unroll
            for (int ct = 0; ct < 8; ++ct) {
                bf16x8 bh = *(const bf16x8*)(bb[ct] + kw);
                bf16x8 bl = *(const bf16x8*)(bb[ct] + kw + K);
                acc[0][ct] = __builtin_amdgcn_mfma_f32_16x16x32_bf16(ah0, bh, acc[0][ct], 0, 0, 0);
                acc[1][ct] = __builtin_amdgcn_mfma_f32_16x16x32_bf16(ah1, bh, acc[1][ct], 0, 0, 0);
                acc[0][ct] = __builtin_amdgcn_mfma_f32_16x16x32_bf16(al0, bh, acc[0][ct], 0, 0, 0);
                acc[1][ct] = __builtin_amdgcn_mfma_f32_16x16x32_bf16(al1, bh, acc[1][ct], 0, 0, 0);
                acc[0][ct] = __builtin_amdgcn_mfma_f32_16x16x32_bf16(ah0, bl, acc[0][ct], 0, 0, 0);
                acc[1][ct] = __builtin_amdgcn_mfma_f32_16x16x32_bf16(ah1, bl, acc[1][ct], 0, 0, 0);
            }
        }
    }

    // ---- epilogue: +bias, store (row-major or LDS-transposed), per-channel stats ----
    float ssum[8], ssq[8];
#pragma unroll
    for (int ct = 0; ct < 8; ++ct) { ssum[ct] = 0.f; ssq[ct] = 0.f; }

#pragma unroll
    for (int ct = 0; ct < 8; ++ct) {
        const float bia = bias[ct * 16 + lr];
#pragma unroll
        for (int t = 0; t < 2; ++t) {
#pragma unroll
            for (int r = 0; r < 4; ++r) {
                const int row = r0 + t * 16 + lg * 4 + r;   // C/D: row=(lane>>4)*4+reg, col=lane&15
                const float v = acc[t][ct][r] + bia;
                const bool ok = (row < VP);
                if constexpr (TRANSOUT) {
                    lt[w * 32 + t * 16 + lg * 4 + r][ct * 16 + lr] = v;
                } else {
                    if (ok) y[((size_t)b * VP + row) * 128 + ct * 16 + lr] = v;
                }
                if (ok) { ssum[ct] += v; ssq[ct] += v * v; }
            }
        }
    }
#pragma unroll
    for (int ct = 0; ct < 8; ++ct) {
        float s = ssum[ct], q = ssq[ct];
        s += __shfl_xor(s, 16, 64); s += __shfl_xor(s, 32, 64);
        q += __shfl_xor(q, 16, 64); q += __shfl_xor(q, 32, 64);
        if (l < 16) {
            atomicAdd(&gsum[b * 128 + ct * 16 + l], s);
            atomicAdd(&gsq [b * 128 + ct * 16 + l], q);
        }
    }
    if constexpr (TRANSOUT) {
        __syncthreads();
#pragma unroll
        for (int u = 0; u < 64; ++u) {
            const int idx = u * 256 + tid;
            const int ch = idx >> 7, vv = idx & 127;
            if (vp0 + vv < VP)
                y[((size_t)b * 128 + ch) * VP + vp0 + vv] = lt[vv][ch];
        }
    }
}

// ---------------- BN stats -> per-(b,ch) affine ----------------
__global__ void k_finalize(const float* __restrict__ gsum, const float* __restrict__ gsq,
                           const float* __restrict__ gam, const float* __restrict__ bet,
                           float* __restrict__ scale, float* __restrict__ shift)
{
    const int i = blockIdx.x * 256 + threadIdx.x;
    if (i >= NB * 128) return;
    const int o = i & 127;
    const float m   = gsum[i] * (1.f / VP);
    const float var = gsq[i] * (1.f / VP) - m * m;
    const float sc  = gam[o] * rsqrtf(var + EPSbn);
    scale[i] = sc;
    shift[i] = fmaf(-m, sc, bet[o]);
}

// ---------------- BN1+LReLU+split, IN PLACE: y1 f32 row -> same bytes as {hi,lo} pairs ----------------
// Lane reads float2 (8B) and writes ushort4 (8B) to the exact same span -> race-free.
__global__ void k_bn1(void* __restrict__ y1v, const float* __restrict__ sc1,
                      const float* __restrict__ sh1)
{
    const int b = blockIdx.y;
    float2* p = (float2*)y1v + (size_t)b * VP * 64;
    for (int e = blockIdx.x * 256 + threadIdx.x; e < VP * 64; e += gridDim.x * 256) {
        const int c = (e & 63) * 2;
        float2 f = p[e];
        const float2 sc = *(const float2*)(sc1 + b * 128 + c);
        const float2 sh = *(const float2*)(sh1 + b * 128 + c);
        float a0 = fmaf(f.x, sc.x, sh.x); a0 = (a0 >= 0.f) ? a0 : 0.2f * a0;
        float a1 = fmaf(f.y, sc.y, sh.y); a1 = (a1 >= 0.f) ? a1 : 0.2f * a1;
        const ushort2 s0 = splitf(a0), s1 = splitf(a1);
        ushort4 o; o.x = s0.x; o.y = s0.y; o.z = s1.x; o.w = s1.y;
        *(ushort4*)(p + e) = o;
    }
}

// ---------------- BN2 + LReLU in place on d_out (B,128,VP) ----------------
__global__ void k_bnout(float* __restrict__ out, const float* __restrict__ scale,
                        const float* __restrict__ shift)
{
    const int bo = blockIdx.x;
    const float sc = scale[bo], sh = shift[bo];
    float* p = out + (size_t)bo * VP;
    for (int v = threadIdx.x; v < VP; v += 256) {
        float xv = fmaf(p[v], sc, sh);
        p[v] = (xv >= 0.f) ? xv : 0.2f * xv;
    }
}

extern "C" void kernel_launch(void* const* d_in, const int* in_sizes, int n_in,
                              void* d_out, int out_size, void* d_ws, size_t ws_size,
                              hipStream_t stream)
{
    (void)in_sizes; (void)n_in; (void)out_size;
    const float* x   = (const float*)d_in[0];
    const int*   pidx= (const int*)d_in[1];
    const int*   nidx= (const int*)d_in[2];
    const float* W1  = (const float*)d_in[3];
    const float* b1  = (const float*)d_in[4];
    const float* g1  = (const float*)d_in[5];
    const float* be1 = (const float*)d_in[6];
    const float* W2  = (const float*)d_in[7];
    const float* b2  = (const float*)d_in[8];
    const float* g2  = (const float*)d_in[9];
    const float* be2 = (const float*)d_in[10];
    float* out = (float*)d_out;
    char*  ws  = (char*)d_ws;

    if (ws_size < WS_NEED) return;   // clean bail, no OOB fault

    u16*   wts2 = (u16*)(ws + OFF_W2);
    u16*   wts1 = (u16*)(ws + OFF_W1);
    float* y1   = (float*)(ws + OFF_Y1);
    float* st   = (float*)(ws + OFF_ST);
    float* sum1 = st;          float* sq1 = st + 2048;
    float* sum2 = st + 4096;   float* sq2 = st + 6144;
    float* sc1  = st + 8192;   float* sh1 = st + 10240;
    float* sc2  = st + 12288;  float* sh2 = st + 14336;
    u16*   h0s  = (u16*)d_out;          // pool..conv1 scratch inside d_out

    hipMemsetAsync(st, 0, 4 * 2048 * sizeof(float), stream);
    k_wsplit<<<224, 256, 0, stream>>>(W1, wts1, 448);
    k_wsplit<<<448, 256, 0, stream>>>(W2, wts2, 896);

    dim3 gpool((VP + 3) / 4, NB);
    if (ws_size >= WS_FAST) {
        float* xT = (float*)(ws + OFF_XT);
        dim3 gt((VIN + 63) / 64, NB);
        k_transpose<<<gt, 256, 0, stream>>>(x, xT);
        k_pool_fast<<<gpool, 256, 0, stream>>>(xT, pidx, h0s);
    } else {
        k_pool_direct<<<gpool, 256, 0, stream>>>(x, pidx, h0s);
    }

    dim3 gconv((VP + 127) / 128, NB);   // 81 x 16
    k_convm<64, false><<<gconv, 256, 0, stream>>>(h0s, nidx, wts1, b1, y1, sum1, sq1);
    k_finalize<<<8, 256, 0, stream>>>(sum1, sq1, g1, be1, sc1, sh1);
    k_bn1<<<dim3(160, NB), 256, 0, stream>>>(y1, sc1, sh1);
    k_convm<128, true><<<gconv, 256, 0, stream>>>((const u16*)y1, nidx, wts2, b2, out, sum2, sq2);
    k_finalize<<<8, 256, 0, stream>>>(sum2, sq2, g2, be2, sc2, sh2);
    k_bnout<<<2048, 256, 0, stream>>>(out, sc2, sh2);
}

// Round 5
// 1002.333 us; speedup vs baseline: 1.5948x; 1.0309x over previous
//
#include <hip/hip_runtime.h>
#include <hip/hip_bf16.h>

#define NB 16
#define VIN 40962
#define VP 10242
#define EPSbn 1e-5f

typedef __attribute__((ext_vector_type(8))) short bf16x8;  // 8 bf16 = 4 VGPR
typedef __attribute__((ext_vector_type(4))) float f32x4;   // MFMA C/D
typedef unsigned short u16;

// ---------------- workspace layout (bytes) ----------------
static constexpr size_t OFF_W2 = 0;                                    // 458,752 B
static constexpr size_t OFF_W1 = 458752;                               // 229,376 B
static constexpr size_t OFF_Y1 = 688128;
static constexpr size_t OFF_ST = OFF_Y1 + (size_t)NB * VP * 128 * 4;   // 84,590,592
static constexpr size_t WS_NEED = OFF_ST + 8 * (size_t)NB * 128 * 4;   // 84,656,128
static constexpr size_t OFF_XT = WS_NEED;
static constexpr size_t WS_FAST = OFF_XT + (size_t)NB * VIN * 64 * 4;  // ~252 MB

// ---------------- bf16 split helpers (RNE) ----------------
__device__ __forceinline__ u16 f2bf(float f) {
    unsigned u; __builtin_memcpy(&u, &f, 4);
    u = u + 0x7FFF + ((u >> 16) & 1);
    return (u16)(u >> 16);
}
__device__ __forceinline__ float bf2f(u16 h) {
    unsigned u = ((unsigned)h) << 16; float f; __builtin_memcpy(&f, &u, 4); return f;
}
__device__ __forceinline__ ushort2 splitf(float f) {
    u16 h = f2bf(f);
    u16 l = f2bf(f - bf2f(h));
    ushort2 r; r.x = h; r.y = l; return r;
}

// ---------------- W prep: W[K][128] f32 -> fragment-linear bf16 hi/lo planes ----------
// Layout (u16 units): plane p in {0(hi),1(lo)} at p*128*K; within plane:
// off = ((ct*(K/32) + kt) << 9) + lane*8 + e, lane = lg*16 + lr, o = ct*16+lr,
// k = kt*32 + lg*8 + e. A wave's B-frag load (64 lanes x 16B) is one contiguous 1KB.
__global__ void k_wsplit(const float* __restrict__ W, u16* __restrict__ wts, int K)
{
    int idx = blockIdx.x * 256 + threadIdx.x;
    if (idx >= K * 128) return;
    int k = idx >> 7, o = idx & 127;
    int ct = o >> 4, lr = o & 15, kt = k >> 5, lg = (k >> 3) & 3, e = k & 7;
    size_t off = ((size_t)(ct * (K >> 5) + kt) << 9) + (lg * 16 + lr) * 8 + e;
    ushort2 s = splitf(W[idx]);
    wts[off]                  = s.x;
    wts[off + (size_t)128 * K] = s.y;
}

// ---------------- tiled transpose: x (B,64,VIN) -> xT (B,VIN,64) f32 ----------------
__global__ void k_transpose(const float* __restrict__ x, float* __restrict__ xT)
{
    __shared__ float t[64][65];
    const int b   = blockIdx.y;
    const int v0  = blockIdx.x * 64;
    const int tid = threadIdx.x;
    const int lc  = tid & 63;
    const int lw  = tid >> 6;
    const float* xb = x + (size_t)b * 64 * VIN;
#pragma unroll
    for (int u = 0; u < 16; ++u) {
        const int c = lw * 16 + u;
        const int v = v0 + lc;
        t[c][lc] = (v < VIN) ? xb[(size_t)c * VIN + v] : 0.f;
    }
    __syncthreads();
    float* xTb = xT + (size_t)b * VIN * 64;
#pragma unroll
    for (int u = 0; u < 16; ++u) {
        const int v = v0 + lw * 16 + u;
        if (v < VIN) xTb[(size_t)v * 64 + lc] = t[lc][lw * 16 + u];
    }
}

// ---------------- mean-pool -> h0s (B,VP, planar hi[64] lo[64] u16 rows) -------------
__global__ void k_pool_fast(const float* __restrict__ xT, const int* __restrict__ pidx,
                            u16* __restrict__ h0s)
{
    const int b  = blockIdx.y;
    const int vp = blockIdx.x * 4 + (threadIdx.x >> 6);
    const int c  = threadIdx.x & 63;
    if (vp >= VP) return;
    const float* xb = xT + (size_t)b * VIN * 64;
    float s = 0.f;
#pragma unroll
    for (int j = 0; j < 7; ++j) {
        const int id = pidx[vp * 7 + j];
        s += xb[(size_t)id * 64 + c];
    }
    s *= (1.f / 7.f);
    u16* r = h0s + ((size_t)b * VP + vp) * 128;
    ushort2 sp = splitf(s);
    r[c]      = sp.x;
    r[64 + c] = sp.y;
}

__global__ void k_pool_direct(const float* __restrict__ x, const int* __restrict__ pidx,
                              u16* __restrict__ h0s)
{
    const int b  = blockIdx.y;
    const int vp = blockIdx.x * 4 + (threadIdx.x >> 6);
    const int c  = threadIdx.x & 63;
    if (vp >= VP) return;
    const float* xb = x + (size_t)(b * 64) * VIN;
    float s = 0.f;
#pragma unroll
    for (int j = 0; j < 7; ++j) {
        const int id = pidx[vp * 7 + j];
        s += xb[(size_t)c * VIN + id];
    }
    s *= (1.f / 7.f);
    u16* r = h0s + ((size_t)b * VP + vp) * 128;
    ushort2 sp = splitf(s);
    r[c]      = sp.x;
    r[64 + c] = sp.y;
}

// ---------------- MFMA conv: gather + bf16x3 split GEMM, barrier-free, LDS-free ------
// src rows: planar u16, hi[CIN] then lo[CIN]. wts: fragment-linear (see k_wsplit).
// Flat grid 1296 = 8 XCDs x 162; XCD k owns batches 2k, 2k+1 (L2 locality).
// 4 waves/block, wave = 32 rows x 128 cols (2 x 8 tiles of 16x16).
template<int CIN, bool TRANSOUT>
__global__ __launch_bounds__(256, 4)
void k_convm(const u16* __restrict__ src, const int* __restrict__ nidx,
             const u16* __restrict__ wts, const float* __restrict__ bias,
             float* __restrict__ y, float* __restrict__ gsum, float* __restrict__ gsq)
{
    constexpr int K  = 7 * CIN;
    constexpr int KT = K >> 5;        // k-slices of 32
    constexpr int PER = CIN >> 5;     // k-slices per neighbor

    const int tid = threadIdx.x;
    const int w   = tid >> 6;
    const int l   = tid & 63;
    const int lg  = l >> 4;
    const int lr  = l & 15;

    const int d    = blockIdx.x;      // XCD-affine decode
    const int xcd  = d & 7;
    const int s    = d >> 3;          // 0..161
    const int hi   = (s >= 81) ? 1 : 0;
    const int b    = xcd * 2 + hi;
    const int tile = s - 81 * hi;
    const int vp0  = tile * 128;
    const int r0   = vp0 + w * 32;

    const u16* srcb = src + (size_t)b * VP * (2 * CIN);
    const int vc0 = (r0 + lr      < VP) ? (r0 + lr)      : (VP - 1);
    const int vc1 = (r0 + 16 + lr < VP) ? (r0 + 16 + lr) : (VP - 1);

    int id0[7], id1[7];
#pragma unroll
    for (int j = 0; j < 7; ++j) {
        id0[j] = nidx[vc0 * 7 + j];
        id1[j] = nidx[vc1 * 7 + j];
    }

    f32x4 acc[2][8];
#pragma unroll
    for (int t = 0; t < 2; ++t)
#pragma unroll
        for (int ct = 0; ct < 8; ++ct) acc[t][ct] = (f32x4){0.f, 0.f, 0.f, 0.f};

    const u16* wl = wts + l * 8;      // per-lane fragment base

#pragma unroll
    for (int j = 0; j < 7; ++j) {
        const u16* a0 = srcb + (size_t)id0[j] * (2 * CIN);
        const u16* a1 = srcb + (size_t)id1[j] * (2 * CIN);
#pragma unroll
        for (int ks = 0; ks < PER; ++ks) {
            const int ko = ks * 32 + lg * 8;
            bf16x8 ah0 = *(const bf16x8*)(a0 + ko);
            bf16x8 al0 = *(const bf16x8*)(a0 + CIN + ko);
            bf16x8 ah1 = *(const bf16x8*)(a1 + ko);
            bf16x8 al1 = *(const bf16x8*)(a1 + CIN + ko);
            const int kt = j * PER + ks;
#pragma unroll
            for (int ct = 0; ct < 8; ++ct) {
                const u16* bp = wl + ((size_t)(ct * KT + kt) << 9);
                bf16x8 bh = *(const bf16x8*)bp;
                bf16x8 bl = *(const bf16x8*)(bp + (size_t)128 * K);
                acc[0][ct] = __builtin_amdgcn_mfma_f32_16x16x32_bf16(ah0, bh, acc[0][ct], 0, 0, 0);
                acc[1][ct] = __builtin_amdgcn_mfma_f32_16x16x32_bf16(ah1, bh, acc[1][ct], 0, 0, 0);
                acc[0][ct] = __builtin_amdgcn_mfma_f32_16x16x32_bf16(al0, bh, acc[0][ct], 0, 0, 0);
                acc[1][ct] = __builtin_amdgcn_mfma_f32_16x16x32_bf16(al1, bh, acc[1][ct], 0, 0, 0);
                acc[0][ct] = __builtin_amdgcn_mfma_f32_16x16x32_bf16(ah0, bl, acc[0][ct], 0, 0, 0);
                acc[1][ct] = __builtin_amdgcn_mfma_f32_16x16x32_bf16(ah1, bl, acc[1][ct], 0, 0, 0);
            }
        }
    }

    // ---- epilogue: +bias, store, per-channel stats ----
    float ssum[8], ssq[8];
#pragma unroll
    for (int ct = 0; ct < 8; ++ct) { ssum[ct] = 0.f; ssq[ct] = 0.f; }

#pragma unroll
    for (int ct = 0; ct < 8; ++ct) {
        const float bia = bias[ct * 16 + lr];
#pragma unroll
        for (int t = 0; t < 2; ++t) {
            const int rbase = r0 + t * 16 + lg * 4;   // C/D: row=(lane>>4)*4+reg, col=lane&15
#pragma unroll
            for (int r = 0; r < 4; ++r) {
                const float v = acc[t][ct][r] + bia;
                acc[t][ct][r] = v;
                if (rbase + r < VP) { ssum[ct] += v; ssq[ct] += v * v; }
            }
            if constexpr (TRANSOUT) {
                // transposed store: 4 consecutive vp of one channel -> float4
                float* q = y + ((size_t)b * 128 + ct * 16 + lr) * VP + rbase;
                if (rbase + 3 < VP) {
                    *(float4*)q = (float4){acc[t][ct][0], acc[t][ct][1], acc[t][ct][2], acc[t][ct][3]};
                } else {
#pragma unroll
                    for (int r = 0; r < 4; ++r)
                        if (rbase + r < VP) q[r] = acc[t][ct][r];
                }
            } else {
#pragma unroll
                for (int r = 0; r < 4; ++r)
                    if (rbase + r < VP)
                        y[((size_t)b * VP + rbase + r) * 128 + ct * 16 + lr] = acc[t][ct][r];
            }
        }
    }
#pragma unroll
    for (int ct = 0; ct < 8; ++ct) {
        float su = ssum[ct], q = ssq[ct];
        su += __shfl_xor(su, 16, 64); su += __shfl_xor(su, 32, 64);
        q  += __shfl_xor(q,  16, 64); q  += __shfl_xor(q,  32, 64);
        if (l < 16) {
            atomicAdd(&gsum[b * 128 + ct * 16 + l], su);
            atomicAdd(&gsq [b * 128 + ct * 16 + l], q);
        }
    }
}

// ---------------- BN stats -> per-(b,ch) affine ----------------
__global__ void k_finalize(const float* __restrict__ gsum, const float* __restrict__ gsq,
                           const float* __restrict__ gam, const float* __restrict__ bet,
                           float* __restrict__ scale, float* __restrict__ shift)
{
    const int i = blockIdx.x * 256 + threadIdx.x;
    if (i >= NB * 128) return;
    const int o = i & 127;
    const float m   = gsum[i] * (1.f / VP);
    const float var = gsq[i] * (1.f / VP) - m * m;
    const float sc  = gam[o] * rsqrtf(var + EPSbn);
    scale[i] = sc;
    shift[i] = fmaf(-m, sc, bet[o]);
}

// ---------------- BN1+LReLU+split IN PLACE: f32[128] row -> planar u16 hi/lo --------
// One wave owns one full row (reads issue before stores within the wave -> race-free).
__global__ void k_bn1(float* __restrict__ y1, const float* __restrict__ sc1,
                      const float* __restrict__ sh1)
{
    const int wib = threadIdx.x >> 6;
    const int l   = threadIdx.x & 63;
    for (size_t row = (size_t)blockIdx.x * 4 + wib; row < (size_t)NB * VP;
         row += (size_t)gridDim.x * 4) {
        const int b = (int)(row / VP);
        float2 v  = *(float2*)(y1 + row * 128 + 2 * l);
        float2 sc = *(const float2*)(sc1 + b * 128 + 2 * l);
        float2 sh = *(const float2*)(sh1 + b * 128 + 2 * l);
        float a0 = fmaf(v.x, sc.x, sh.x); a0 = (a0 >= 0.f) ? a0 : 0.2f * a0;
        float a1 = fmaf(v.y, sc.y, sh.y); a1 = (a1 >= 0.f) ? a1 : 0.2f * a1;
        const ushort2 s0 = splitf(a0), s1 = splitf(a1);
        u16* r = (u16*)(y1 + row * 128);
        ushort2 h; h.x = s0.x; h.y = s1.x;
        ushort2 lo; lo.x = s0.y; lo.y = s1.y;
        *(ushort2*)(r + 2 * l)       = h;    // hi plane, ch 2l,2l+1
        *(ushort2*)(r + 128 + 2 * l) = lo;   // lo plane
    }
}

// ---------------- BN2 + LReLU in place on d_out (B,128,VP) ----------------
__global__ void k_bnout(float* __restrict__ out, const float* __restrict__ scale,
                        const float* __restrict__ shift)
{
    const int bo = blockIdx.x;
    const float sc = scale[bo], sh = shift[bo];
    float* p = out + (size_t)bo * VP;
    for (int v = threadIdx.x; v < VP; v += 256) {
        float xv = fmaf(p[v], sc, sh);
        p[v] = (xv >= 0.f) ? xv : 0.2f * xv;
    }
}

extern "C" void kernel_launch(void* const* d_in, const int* in_sizes, int n_in,
                              void* d_out, int out_size, void* d_ws, size_t ws_size,
                              hipStream_t stream)
{
    (void)in_sizes; (void)n_in; (void)out_size;
    const float* x   = (const float*)d_in[0];
    const int*   pidx= (const int*)d_in[1];
    const int*   nidx= (const int*)d_in[2];
    const float* W1  = (const float*)d_in[3];
    const float* b1  = (const float*)d_in[4];
    const float* g1  = (const float*)d_in[5];
    const float* be1 = (const float*)d_in[6];
    const float* W2  = (const float*)d_in[7];
    const float* b2  = (const float*)d_in[8];
    const float* g2  = (const float*)d_in[9];
    const float* be2 = (const float*)d_in[10];
    float* out = (float*)d_out;
    char*  ws  = (char*)d_ws;

    if (ws_size < WS_NEED) return;   // clean bail, no OOB fault

    u16*   wts2 = (u16*)(ws + OFF_W2);
    u16*   wts1 = (u16*)(ws + OFF_W1);
    float* y1   = (float*)(ws + OFF_Y1);
    float* st   = (float*)(ws + OFF_ST);
    float* sum1 = st;          float* sq1 = st + 2048;
    float* sum2 = st + 4096;   float* sq2 = st + 6144;
    float* sc1  = st + 8192;   float* sh1 = st + 10240;
    float* sc2  = st + 12288;  float* sh2 = st + 14336;
    u16*   h0s  = (u16*)d_out;          // pool..conv1 scratch inside d_out

    hipMemsetAsync(st, 0, 4 * 2048 * sizeof(float), stream);
    k_wsplit<<<224, 256, 0, stream>>>(W1, wts1, 448);
    k_wsplit<<<448, 256, 0, stream>>>(W2, wts2, 896);

    dim3 gpool((VP + 3) / 4, NB);
    if (ws_size >= WS_FAST) {
        float* xT = (float*)(ws + OFF_XT);
        dim3 gt((VIN + 63) / 64, NB);
        k_transpose<<<gt, 256, 0, stream>>>(x, xT);
        k_pool_fast<<<gpool, 256, 0, stream>>>(xT, pidx, h0s);
    } else {
        k_pool_direct<<<gpool, 256, 0, stream>>>(x, pidx, h0s);
    }

    k_convm<64, false><<<1296, 256, 0, stream>>>(h0s, nidx, wts1, b1, y1, sum1, sq1);
    k_finalize<<<8, 256, 0, stream>>>(sum1, sq1, g1, be1, sc1, sh1);
    k_bn1<<<2048, 256, 0, stream>>>(y1, sc1, sh1);
    k_convm<128, true><<<1296, 256, 0, stream>>>((const u16*)y1, nidx, wts2, b2, out, sum2, sq2);
    k_finalize<<<8, 256, 0, stream>>>(sum2, sq2, g2, be2, sc2, sh2);
    k_bnout<<<2048, 256, 0, stream>>>(out, sc2, sh2);
}